// Round 1
// 416.939 us; speedup vs baseline: 1.0360x; 1.0360x over previous
//
#include <hip/hip_runtime.h>
#include <hip/hip_bf16.h>

// GraphConvolutionLayer on MI355X (gfx950) — fused single-pass version.
//   scale = 1/(rowsum(adj)+beta);  agg = adj@x + beta*x;  out = (scale*agg)@W + bias
// Design:
//   k1: tile/convert x (8192x256) and W (256x256) fp32 -> bf16 MFMA-B tiled
//       layout [kblk][n16][kg][nl][8] (contiguous global_load_lds staging AND
//       conflict-free b128 B-frag reads).
//   k2 (fused): 256 blocks x 512 thr (8 waves, 2M x 4N). Block owns 32 rows x
//       full K=8192, so rowsum/scale/beta-add/W-GEMM all fuse in the epilogue —
//       no partial-aggregate HBM round-trip, no stage2 kernel.
//       Main loop: BK=64, TRIPLE-buffered LDS, ONE raw s_barrier per step with
//       counted s_waitcnt vmcnt(5) (loads stay 2 steps in flight; never drains
//       to 0 in the main loop). adj read exactly once (268 MB -> ~43 us floor).
//       A-tile staged fp32 with XOR-swizzled per-lane global source (m173
//       pattern) so b128 A-frag reads are quarter-wave conflict-free; rowsum
//       fused from wn==0 waves' A-frags (fp32, pre-pack).
//   Epilogue: x-tile staged to LDS, g = scale*(acc + beta*x) -> bf16 -> LDS
//       (XOR-swizzled), then (32x256)@(256x256) bf16 MFMA with W-frags straight
//       from L2-hot wbt; bias in fp32.

typedef __attribute__((ext_vector_type(8))) short  short8;
typedef __attribute__((ext_vector_type(4))) float  floatx4;

#define N_NODES 8192
#define F_DIM   256
#define BK      64
#define NSTEPS  (N_NODES / BK)   // 128

#define ASYNC16(g, l)                                                          \
  __builtin_amdgcn_global_load_lds(                                           \
      (const __attribute__((address_space(1))) void*)(g),                     \
      (__attribute__((address_space(3))) void*)(l), 16, 0, 0)

// fp32 -> bf16 round-to-nearest-even (no NaN handling; inputs are finite)
__device__ __forceinline__ unsigned short f2bf(float f) {
  unsigned u = __float_as_uint(f);
  return (unsigned short)((u + 0x7FFFu + ((u >> 16) & 1u)) >> 16);
}

__device__ __forceinline__ short8 pack_bf16x8(floatx4 a, floatx4 b) {
  short8 r;
  r[0] = (short)f2bf(a.x);
  r[1] = (short)f2bf(a.y);
  r[2] = (short)f2bf(a.z);
  r[3] = (short)f2bf(a.w);
  r[4] = (short)f2bf(b.x);
  r[5] = (short)f2bf(b.y);
  r[6] = (short)f2bf(b.z);
  r[7] = (short)f2bf(b.w);
  return r;
}

// ---------------------------------------------------------------------------
// k1: fp32 [K][256] -> bf16 tiled [K/32][n16(16)][kg(4)][nl(16)][8]
// ---------------------------------------------------------------------------
__global__ __launch_bounds__(256) void tile_bf16_kernel(
    const float* __restrict__ src, unsigned short* __restrict__ dst, int K) {
  const int Nn = F_DIM;
  int cid = blockIdx.x * 256 + threadIdx.x;      // one 8-element chunk
  int per_kblk = Nn * 4;                         // 1024 chunks per 32-k block
  int kblk = cid / per_kblk;
  int rem  = cid - kblk * per_kblk;
  int n16 = rem >> 6;
  int kg  = (rem >> 4) & 3;
  int nl  = rem & 15;
  int n = n16 * 16 + nl;
  int k = kblk * 32 + kg * 8;
  const float* s = src + (size_t)k * Nn + n;
  floatx4 v0, v1;
  v0.x = s[0];
  v0.y = s[(size_t)Nn];
  v0.z = s[(size_t)2 * Nn];
  v0.w = s[(size_t)3 * Nn];
  v1.x = s[(size_t)4 * Nn];
  v1.y = s[(size_t)5 * Nn];
  v1.z = s[(size_t)6 * Nn];
  v1.w = s[(size_t)7 * Nn];
  *(short8*)(dst + (size_t)cid * 8) = pack_bf16x8(v0, v1);
}

// ---------------------------------------------------------------------------
// k2: fused  agg + rowsum + scale + W-GEMM
// grid 256 blocks x 512 threads; LDS 120.25 KB -> 1 block/CU, 8 waves.
// ---------------------------------------------------------------------------
__global__ __launch_bounds__(512, 2) void fused_kernel(
    const float* __restrict__ adj, const unsigned short* __restrict__ xbt,
    const float* __restrict__ x, const float* __restrict__ beta,
    const float* __restrict__ bias, const unsigned short* __restrict__ wbt,
    float* __restrict__ out) {
  // layout: A bufs 3 x 8 KB @ 0 | B bufs 3 x 32 KB @ 24576 | scale/beta @ 122880
  // epilogue overlays: g-tile (16 KB bf16) @ 0, x-tile (32 KB fp32) @ 24576
  __shared__ __attribute__((aligned(16))) char smem[123136];
  float* sscale = (float*)(smem + 122880);
  float* sbeta  = (float*)(smem + 123008);

  const int tid = threadIdx.x;
  const int w   = tid >> 6;      // 0..7
  const int l   = tid & 63;
  const int kq  = l >> 4;        // MFMA k-quad
  const int ml  = l & 15;
  const int wm  = w >> 2;        // 0..1  (M strip)
  const int wn  = w & 3;         // 0..3  (N strip)
  const int m0  = blockIdx.x * 32;

  // ---- staging geometry ----
  // A: 512 16B-chunks = 32 rows x 16 col-groups; thread t -> slot(row=t>>4, grp=t&15)
  //    source col-group = grp ^ (row&7)  (inverse-swizzled source, linear LDS dest)
  const int arow = tid >> 4;
  const int agrp = tid & 15;
  const float* asrc_base =
      adj + (size_t)(m0 + arow) * N_NODES + ((agrp ^ (arow & 7)) << 2);
  // B: xbt is MFMA-tiled; one step = 2 kblks = 32 KB contiguous, copied linearly
  const unsigned short* bsrc_base = xbt + (size_t)tid * 8;

  // A-frag LDS offsets (floats): row=wm*16+ml, k-groups (kb*8+2kq, +1), XOR-swz
  const int frow = wm * 16 + ml;
  int aoff[2][2];
#pragma unroll
  for (int kb = 0; kb < 2; ++kb) {
    int g0 = kb * 8 + kq * 2;
    aoff[kb][0] = frow * 64 + (((g0)     ^ (frow & 7)) << 2);
    aoff[kb][1] = frow * 64 + (((g0 + 1) ^ (frow & 7)) << 2);
  }
  // B-frag base offset (ushorts): n16 = wn*4+nf
  const int boffbase = wn * 2048 + kq * 128 + ml * 8;

  floatx4 acc[4];
  const floatx4 zf4 = {0.f, 0.f, 0.f, 0.f};
#pragma unroll
  for (int nf = 0; nf < 4; ++nf) acc[nf] = zf4;
  float rsum = 0.f;

  // ---- prologue: stage steps 0 and 1 into buffers 0 and 1 ----
#pragma unroll
  for (int s = 0; s < 2; ++s) {
    ASYNC16(asrc_base + s * BK, smem + s * 8192 + (w << 10));
    const unsigned short* bs = bsrc_base + (size_t)s * 16384;
    char* bd = smem + 24576 + s * 32768 + (w << 10);
#pragma unroll
    for (int q = 0; q < 4; ++q) ASYNC16(bs + q * 4096, bd + q * 8192);
  }

  auto compute = [&](int cur) {
    const float* Af = (const float*)(smem + cur * 8192);
    const unsigned short* Bf = (const unsigned short*)(smem + 24576 + cur * 32768);
    short8 af[2];
#pragma unroll
    for (int kb = 0; kb < 2; ++kb) {
      floatx4 a0 = *(const floatx4*)(Af + aoff[kb][0]);
      floatx4 a1 = *(const floatx4*)(Af + aoff[kb][1]);
      if (wn == 0)   // fused rowsum (fp32, pre-pack); kq x kb x 8 covers all 64 k
        rsum += (a0.x + a0.y + a0.z + a0.w) + (a1.x + a1.y + a1.z + a1.w);
      af[kb] = pack_bf16x8(a0, a1);
    }
#pragma unroll
    for (int nf = 0; nf < 4; ++nf) {
      short8 b0 = *(const short8*)(Bf + boffbase + nf * 512);
      short8 b1 = *(const short8*)(Bf + 8192 + boffbase + nf * 512);
      acc[nf] = __builtin_amdgcn_mfma_f32_16x16x32_bf16(af[0], b0, acc[nf], 0, 0, 0);
      acc[nf] = __builtin_amdgcn_mfma_f32_16x16x32_bf16(af[1], b1, acc[nf], 0, 0, 0);
    }
  };

  // ---- main loop: triple-buffer, 1 barrier/step, counted vmcnt (never 0) ----
  int cur = 0, stg = 2;
  for (int s = 0; s < NSTEPS - 2; ++s) {
    // wait: everything except the newest 5 loads (issued last iter) has landed
    // -> buffer `cur` (staged 2 iters ago) is ready; barrier publishes it.
    asm volatile("s_waitcnt vmcnt(5)\n\ts_barrier" ::: "memory");
    // stage step s+2 into buffer stg
    ASYNC16(asrc_base + (s + 2) * BK, smem + stg * 8192 + (w << 10));
    {
      const unsigned short* bs = bsrc_base + (size_t)(s + 2) * 16384;
      char* bd = smem + 24576 + stg * 32768 + (w << 10);
#pragma unroll
      for (int q = 0; q < 4; ++q) ASYNC16(bs + q * 4096, bd + q * 8192);
    }
    compute(cur);
    cur = cur + 1; if (cur == 3) cur = 0;
    stg = stg + 1; if (stg == 3) stg = 0;
  }
  // peeled tail: nothing left to stage; full drain is cheap here (2 iters)
  for (int s = NSTEPS - 2; s < NSTEPS; ++s) {
    asm volatile("s_waitcnt vmcnt(0)\n\ts_barrier" ::: "memory");
    compute(cur);
    cur = cur + 1; if (cur == 3) cur = 0;
  }

  __syncthreads();   // full drain: LDS reusable by epilogue overlays

  // ---- epilogue ----
  // stage x-tile (32 rows x 256 fp32 = 32 KB) into B-area, linear
  {
    const float* xs = x + (size_t)m0 * F_DIM + tid * 4;
    char* xd = smem + 24576 + (w << 10);
#pragma unroll
    for (int q = 0; q < 4; ++q) ASYNC16(xs + q * 2048, xd + q * 8192);
  }
  // rowsum -> scale (waves 0 and 4 hold A-row partials for strips 0/1)
  if (wn == 0) {
    float rs = rsum;
    rs += __shfl_xor(rs, 16);
    rs += __shfl_xor(rs, 32);
    if (l < 16) {
      float b = beta[m0 + wm * 16 + l];
      sbeta[wm * 16 + l]  = b;
      sscale[wm * 16 + l] = 1.0f / (rs + b);
    }
  }
  __syncthreads();   // x landed (vmcnt(0) before barrier), scale/beta visible

  // g = scale*(acc + beta*x) -> bf16 -> A-area, chunk-XOR-swizzled by row
  const float* xl = (const float*)(smem + 24576);
  unsigned short* G = (unsigned short*)smem;
#pragma unroll
  for (int nf = 0; nf < 4; ++nf) {
    int col = wn * 64 + nf * 16 + ml;
    int chunk = col >> 3;
#pragma unroll
    for (int r = 0; r < 4; ++r) {
      int row = wm * 16 + kq * 4 + r;   // C/D layout: col=lane&15, row=quad*4+reg
      float g = sscale[row] * (acc[nf][r] + sbeta[row] * xl[row * F_DIM + col]);
      G[row * 256 + (((chunk ^ (row & 7)) << 3) | (col & 7))] = f2bf(g);
    }
  }
  __syncthreads();

  // GEMM2: out = g @ W + bias  (W-frags straight from L2-hot wbt)
  floatx4 acc2[4];
#pragma unroll
  for (int nf = 0; nf < 4; ++nf) acc2[nf] = zf4;
  const int grow = wm * 16 + ml;
#pragma unroll
  for (int s2 = 0; s2 < 8; ++s2) {
    short8 ag = *(const short8*)(G + grow * 256 +
                                 (((s2 * 4 + kq) ^ (grow & 7)) << 3));
    const unsigned short* wb = wbt + s2 * 8192 + boffbase;
#pragma unroll
    for (int nf = 0; nf < 4; ++nf) {
      short8 bv = *(const short8*)(wb + nf * 512);
      acc2[nf] = __builtin_amdgcn_mfma_f32_16x16x32_bf16(ag, bv, acc2[nf], 0, 0, 0);
    }
  }
#pragma unroll
  for (int nf = 0; nf < 4; ++nf) {
    int col = wn * 64 + nf * 16 + ml;
    float bv = bias[col];
#pragma unroll
    for (int r = 0; r < 4; ++r) {
      int row = m0 + wm * 16 + kq * 4 + r;
      out[(size_t)row * F_DIM + col] = acc2[nf][r] + bv;
    }
  }
}

// ---------------------------------------------------------------------------
extern "C" void kernel_launch(void* const* d_in, const int* in_sizes, int n_in,
                              void* d_out, int out_size, void* d_ws, size_t ws_size,
                              hipStream_t stream) {
  const float* x    = (const float*)d_in[0];  // [8192][256]
  const float* adj  = (const float*)d_in[1];  // [8192][8192]
  const float* kern = (const float*)d_in[2];  // [256][256]
  const float* bias = (const float*)d_in[3];  // [256]
  const float* beta = (const float*)d_in[4];  // [8192]
  float* out = (float*)d_out;

  char* ws = (char*)d_ws;
  unsigned short* xbt = (unsigned short*)ws;                 // 4 MB
  unsigned short* wbt = xbt + (size_t)N_NODES * F_DIM;       // 128 KB

  tile_bf16_kernel<<<(N_NODES * F_DIM / 8) / 256, 256, 0, stream>>>(x, xbt, N_NODES);
  tile_bf16_kernel<<<(F_DIM * F_DIM / 8) / 256, 256, 0, stream>>>(kern, wbt, F_DIM);
  fused_kernel<<<256, 512, 0, stream>>>(adj, xbt, x, beta, bias, wbt, out);
}